// Round 2
// baseline (225.344 us; speedup 1.0000x reference)
//
#include <hip/hip_runtime.h>
#include <math.h>

#define NBINS 10
#define ALPHA 0.75f

// Workspace layout: float sums[NBINS]; unsigned int counts[NBINS];

__device__ __forceinline__ void ghm_process(float x1, float x2, float t,
                                            float* __restrict__ s,
                                            unsigned int* __restrict__ c) {
    float diff = x1 - x2;
    float loss = fmaxf(0.0f, -t * diff);           // MARGIN = 0
    float es   = 2.0f * t - 1.0f;                  // reference quirk (t is +-1 already)
    float x    = -diff * es;                       // sigmoid argument
    float g    = 1.0f / (1.0f + __expf(-x));
    int bin    = (int)floorf(g * 10.0f);
    bin = min(max(bin, 0), NBINS - 1);
    // Fully-unrolled predicated accumulate: all array indices are
    // compile-time constants -> stays in VGPRs (no scratch, rule #20).
#pragma unroll
    for (int b = 0; b < NBINS; ++b) {
        bool m = (bin == b);
        s[b] += m ? loss : 0.0f;
        c[b] += m ? 1u : 0u;
    }
}

__global__ __launch_bounds__(256) void ghm_hist_kernel(
        const float* __restrict__ o1, const float* __restrict__ o2,
        const float* __restrict__ tg,
        float* __restrict__ g_sums, unsigned int* __restrict__ g_counts,
        int n) {
    float s[NBINS];
    unsigned int c[NBINS];
#pragma unroll
    for (int b = 0; b < NBINS; ++b) { s[b] = 0.0f; c[b] = 0u; }

    const int n4 = n >> 2;
    const float4* __restrict__ v1 = (const float4*)o1;
    const float4* __restrict__ v2 = (const float4*)o2;
    const float4* __restrict__ vt = (const float4*)tg;

    const int idx    = blockIdx.x * blockDim.x + threadIdx.x;
    const int stride = gridDim.x * blockDim.x;

    for (int i = idx; i < n4; i += stride) {
        float4 a = v1[i];
        float4 b = v2[i];
        float4 t = vt[i];
        ghm_process(a.x, b.x, t.x, s, c);
        ghm_process(a.y, b.y, t.y, s, c);
        ghm_process(a.z, b.z, t.z, s, c);
        ghm_process(a.w, b.w, t.w, s, c);
    }
    // tail (n not divisible by 4)
    const int tail_base = n4 << 2;
    const int tail = n - tail_base;
    if (idx < tail) {
        ghm_process(o1[tail_base + idx], o2[tail_base + idx], tg[tail_base + idx], s, c);
    }

    // Wave-level reduction (64 lanes)
#pragma unroll
    for (int b = 0; b < NBINS; ++b) {
        float sv = s[b];
        unsigned int cv = c[b];
#pragma unroll
        for (int off = 32; off > 0; off >>= 1) {
            sv += __shfl_down(sv, off, 64);
            cv += __shfl_down(cv, off, 64);
        }
        s[b] = sv;
        c[b] = cv;
    }

    // Cross-wave reduction via LDS (4 waves per 256-thread block)
    __shared__ float        ls[4][NBINS];
    __shared__ unsigned int lc[4][NBINS];
    const int wave = threadIdx.x >> 6;
    const int lane = threadIdx.x & 63;
    if (lane == 0) {
#pragma unroll
        for (int b = 0; b < NBINS; ++b) { ls[wave][b] = s[b]; lc[wave][b] = c[b]; }
    }
    __syncthreads();
    if (threadIdx.x < NBINS) {
        float sv = 0.0f;
        unsigned int cv = 0u;
#pragma unroll
        for (int w = 0; w < 4; ++w) { sv += ls[w][threadIdx.x]; cv += lc[w][threadIdx.x]; }
        atomicAdd(&g_sums[threadIdx.x], sv);
        atomicAdd(&g_counts[threadIdx.x], cv);
    }
}

__global__ void ghm_final_kernel(const float* __restrict__ g_sums,
                                 const unsigned int* __restrict__ g_counts,
                                 float* __restrict__ out, float inv_n) {
    if (threadIdx.x == 0 && blockIdx.x == 0) {
        float acc = 0.0f;
#pragma unroll
        for (int b = 0; b < NBINS; ++b) {
            float tot = fmaxf((float)g_counts[b], 1.0f);
            float w = powf(tot, -ALPHA);
            acc += g_sums[b] * w;
        }
        out[0] = acc * inv_n;
    }
}

extern "C" void kernel_launch(void* const* d_in, const int* in_sizes, int n_in,
                              void* d_out, int out_size, void* d_ws, size_t ws_size,
                              hipStream_t stream) {
    const float* o1 = (const float*)d_in[0];
    const float* o2 = (const float*)d_in[1];
    const float* tg = (const float*)d_in[2];
    float* out = (float*)d_out;
    const int n = in_sizes[0];

    float* g_sums = (float*)d_ws;
    unsigned int* g_counts = (unsigned int*)((char*)d_ws + NBINS * sizeof(float));

    // Workspace is re-poisoned to 0xAA before every timed call — zero it.
    hipMemsetAsync(d_ws, 0, NBINS * (sizeof(float) + sizeof(unsigned int)), stream);

    const int block = 256;
    int grid = (n / 4 + block - 1) / block;
    if (grid > 2048) grid = 2048;

    ghm_hist_kernel<<<grid, block, 0, stream>>>(o1, o2, tg, g_sums, g_counts, n);
    ghm_final_kernel<<<1, 64, 0, stream>>>(g_sums, g_counts, out, 1.0f / (float)n);
}

// Round 3
// 207.708 us; speedup vs baseline: 1.0849x; 1.0849x over previous
//
#include <hip/hip_runtime.h>
#include <math.h>

#define NBINS 10
#define ALPHA 0.75f

// Cumulative-threshold formulation:
//   bin(g) = floor(g*10)  with g = sigmoid(x)  ==>  bin >= k  <=>  x >= logit(k/10)
//   cc[k-1] counts elements with x >= L_k  (k = 1..9)
//   ss[j]   sums  loss over elements with x >= L_{5+j}  (j = 0..4; loss==0 for x<0)
// Per-bin values are exact (counts) / tolerant (sums) differences of cumulatives.

__device__ __forceinline__ void ghm_elem(float x1, float x2, float t,
                                         unsigned int* __restrict__ cc,
                                         float* __restrict__ ss) {
    // logit thresholds ln(k/(10-k)), k = 1..9
    const float L[9] = {-2.19722458f, -1.38629436f, -0.84729786f, -0.40546511f,
                         0.0f,         0.40546511f,  0.84729786f,  1.38629436f,
                         2.19722458f};
    float diff = x1 - x2;
    float es   = __builtin_fmaf(2.0f, t, -1.0f);   // reference quirk: {-3, +1}
    float x    = -diff * es;                       // sigmoid argument
    float loss = fmaxf(0.0f, -t * diff);           // MARGIN = 0
#pragma unroll
    for (int k = 0; k < 9; ++k)
        cc[k] += (x >= L[k]) ? 1u : 0u;            // compare + add-carry, independent
#pragma unroll
    for (int j = 0; j < 5; ++j)
        ss[j] += (x >= L[4 + j]) ? loss : 0.0f;    // reuses the k=5..9 compares
}

__global__ __launch_bounds__(256) void ghm_hist_kernel(
        const float* __restrict__ o1, const float* __restrict__ o2,
        const float* __restrict__ tg,
        unsigned int* __restrict__ g_cc, float* __restrict__ g_ss,
        int n) {
    unsigned int cc[9];
    float ss[5];
#pragma unroll
    for (int k = 0; k < 9; ++k) cc[k] = 0u;
#pragma unroll
    for (int j = 0; j < 5; ++j) ss[j] = 0.0f;

    const int n4 = n >> 2;
    const float4* __restrict__ v1 = (const float4*)o1;
    const float4* __restrict__ v2 = (const float4*)o2;
    const float4* __restrict__ vt = (const float4*)tg;

    const int idx    = blockIdx.x * blockDim.x + threadIdx.x;
    const int stride = gridDim.x * blockDim.x;

    // 2x-unrolled grid-stride loop: 6 float4 loads in flight per iteration.
    int i = idx;
    for (; i + stride < n4; i += 2 * stride) {
        float4 a0 = v1[i];
        float4 b0 = v2[i];
        float4 t0 = vt[i];
        float4 a1 = v1[i + stride];
        float4 b1 = v2[i + stride];
        float4 t1 = vt[i + stride];
        ghm_elem(a0.x, b0.x, t0.x, cc, ss);
        ghm_elem(a0.y, b0.y, t0.y, cc, ss);
        ghm_elem(a0.z, b0.z, t0.z, cc, ss);
        ghm_elem(a0.w, b0.w, t0.w, cc, ss);
        ghm_elem(a1.x, b1.x, t1.x, cc, ss);
        ghm_elem(a1.y, b1.y, t1.y, cc, ss);
        ghm_elem(a1.z, b1.z, t1.z, cc, ss);
        ghm_elem(a1.w, b1.w, t1.w, cc, ss);
    }
    for (; i < n4; i += stride) {
        float4 a0 = v1[i];
        float4 b0 = v2[i];
        float4 t0 = vt[i];
        ghm_elem(a0.x, b0.x, t0.x, cc, ss);
        ghm_elem(a0.y, b0.y, t0.y, cc, ss);
        ghm_elem(a0.z, b0.z, t0.z, cc, ss);
        ghm_elem(a0.w, b0.w, t0.w, cc, ss);
    }
    // scalar tail (n % 4 != 0; not hit for N = 2^24 but kept for generality)
    const int tail_base = n4 << 2;
    if (idx < n - tail_base) {
        ghm_elem(o1[tail_base + idx], o2[tail_base + idx], tg[tail_base + idx], cc, ss);
    }

    // Wave-level reduction (64 lanes)
#pragma unroll
    for (int k = 0; k < 9; ++k) {
        unsigned int v = cc[k];
#pragma unroll
        for (int off = 32; off > 0; off >>= 1) v += __shfl_down(v, off, 64);
        cc[k] = v;
    }
#pragma unroll
    for (int j = 0; j < 5; ++j) {
        float v = ss[j];
#pragma unroll
        for (int off = 32; off > 0; off >>= 1) v += __shfl_down(v, off, 64);
        ss[j] = v;
    }

    // Cross-wave reduction via LDS (4 waves / block)
    __shared__ unsigned int lc[4][9];
    __shared__ float        ls[4][5];
    const int wave = threadIdx.x >> 6;
    const int lane = threadIdx.x & 63;
    if (lane == 0) {
#pragma unroll
        for (int k = 0; k < 9; ++k) lc[wave][k] = cc[k];
#pragma unroll
        for (int j = 0; j < 5; ++j) ls[wave][j] = ss[j];
    }
    __syncthreads();
    if (threadIdx.x < 9) {
        unsigned int v = 0u;
#pragma unroll
        for (int w = 0; w < 4; ++w) v += lc[w][threadIdx.x];
        atomicAdd(&g_cc[threadIdx.x], v);
    } else if (threadIdx.x >= 16 && threadIdx.x < 21) {
        const int j = threadIdx.x - 16;
        float v = 0.0f;
#pragma unroll
        for (int w = 0; w < 4; ++w) v += ls[w][j];
        atomicAdd(&g_ss[j], v);
    }
}

__global__ void ghm_final_kernel(const unsigned int* __restrict__ g_cc,
                                 const float* __restrict__ g_ss,
                                 float* __restrict__ out, int n) {
    if (threadIdx.x == 0 && blockIdx.x == 0) {
        // Reconstruct per-bin counts from cumulative counts.
        float tot[NBINS];
        tot[0] = (float)(n - (int)g_cc[0]);
#pragma unroll
        for (int b = 1; b < 9; ++b) tot[b] = (float)(g_cc[b - 1] - g_cc[b]);
        tot[9] = (float)g_cc[8];
        // Per-bin loss sums (bins 5..9 only; loss == 0 below bin 5).
        float s[5];
#pragma unroll
        for (int j = 0; j < 4; ++j) s[j] = g_ss[j] - g_ss[j + 1];
        s[4] = g_ss[4];
        float acc = 0.0f;
#pragma unroll
        for (int j = 0; j < 5; ++j) {
            float t = fmaxf(tot[5 + j], 1.0f);
            acc += s[j] * powf(t, -ALPHA);
        }
        out[0] = acc / (float)n;
    }
}

extern "C" void kernel_launch(void* const* d_in, const int* in_sizes, int n_in,
                              void* d_out, int out_size, void* d_ws, size_t ws_size,
                              hipStream_t stream) {
    const float* o1 = (const float*)d_in[0];
    const float* o2 = (const float*)d_in[1];
    const float* tg = (const float*)d_in[2];
    float* out = (float*)d_out;
    const int n = in_sizes[0];

    unsigned int* g_cc = (unsigned int*)d_ws;                 // 9 u32
    float* g_ss = (float*)((char*)d_ws + 16 * sizeof(unsigned int)); // 5 f32 (16-aligned block)

    // Workspace is re-poisoned to 0xAA before every timed call — zero it.
    hipMemsetAsync(d_ws, 0, 32 * sizeof(unsigned int), stream);

    const int block = 256;
    int grid = (n / 4 + block - 1) / block;
    if (grid > 2048) grid = 2048;

    ghm_hist_kernel<<<grid, block, 0, stream>>>(o1, o2, tg, g_cc, g_ss, n);
    ghm_final_kernel<<<1, 64, 0, stream>>>(g_cc, g_ss, out, n);
}